// Round 2
// baseline (251.007 us; speedup 1.0000x reference)
//
#include <hip/hip_runtime.h>
#include <cstdint>
#include <cstddef>

typedef _Float16 f16;
typedef _Float16 f16x8 __attribute__((ext_vector_type(8)));
typedef _Float16 f16x4 __attribute__((ext_vector_type(4)));
typedef __fp16 h16x2 __attribute__((ext_vector_type(2)));
typedef float f32x4 __attribute__((ext_vector_type(4)));
typedef float f32x16 __attribute__((ext_vector_type(16)));

#define DIM 768
#define NHEAD 12
#define HD 64
#define BATCH 4
#define SEQ 2048
#define MROWS (BATCH*SEQ)   // 8192
#define C3 (3*DIM)          // 2304
#define NBH (BATCH*NHEAD)   // 48

__device__ __forceinline__ f32x4 mfma32(f16x8 a, f16x8 b, f32x4 c) {
  return __builtin_amdgcn_mfma_f32_16x16x32_f16(a, b, c, 0, 0, 0);
}
__device__ __forceinline__ f32x16 mfma3232(f16x8 a, f16x8 b, f32x16 c) {
  return __builtin_amdgcn_mfma_f32_32x32x16_f16(a, b, c, 0, 0, 0);
}

// async global->LDS, 16B per lane; LDS dest = wave-uniform base + lane*16
__device__ __forceinline__ void gl2lds16(const void* g, void* l) {
  __builtin_amdgcn_global_load_lds(
      (const __attribute__((address_space(1))) void*)g,
      (__attribute__((address_space(3))) void*)l, 16, 0, 0);
}

// ---------------- fp32 -> fp16 convert (x, qkv_weight, proj_weight) ----------
__global__ __launch_bounds__(256) void k_convert(
    const float* __restrict__ x, const float* __restrict__ wqkv,
    const float* __restrict__ wproj,
    f16* __restrict__ xh, f16* __restrict__ wqh, f16* __restrict__ wph)
{
  const int NX = MROWS*DIM/4, NW = C3*DIM/4;
  int i = blockIdx.x * 256 + threadIdx.x;
  const float4* src; f16* dst; int idx;
  if (i < NX)         { src = (const float4*)x;     dst = xh;  idx = i; }
  else if (i < NX+NW) { src = (const float4*)wqkv;  dst = wqh; idx = i - NX; }
  else                { src = (const float4*)wproj; dst = wph; idx = i - NX - NW; }
  float4 v = src[idx];
  union { f16 h[4]; uint64_t u; } r;
  r.h[0] = (f16)v.x; r.h[1] = (f16)v.y; r.h[2] = (f16)v.z; r.h[3] = (f16)v.w;
  ((uint64_t*)dst)[idx] = r.u;
}

// ---- 128x128 GEMM core (C = A*B^T, both K-contig), BK=32, dbuf, 1 barrier/iter
__device__ __forceinline__ void gemm_tile(
    const f16* __restrict__ A, const f16* __restrict__ B,
    int lda, int ldb, int K, int am0, int bn0,
    f16* smem, f32x4 acc[4][4])
{
  f16* sA0 = smem;         f16* sA1 = smem + 4096;
  f16* sB0 = smem + 8192;  f16* sB1 = smem + 12288;
  const int tid = threadIdx.x, wid = tid >> 6;
  const int lane = tid & 63, lane15 = lane & 15, quad = lane >> 4;
  const int wm = wid >> 1, wn = wid & 1;

  auto stage = [&](int k0, f16* sA, f16* sB) {
    #pragma unroll
    for (int i = 0; i < 2; i++) {
      int j = i*256 + tid;
      int row = j >> 2;
      int sc  = (j & 3) ^ ((row >> 1) & 3);
      gl2lds16(A + (size_t)(am0 + row)*lda + k0 + sc*8, sA + (i*256 + wid*64)*8);
      gl2lds16(B + (size_t)(bn0 + row)*ldb + k0 + sc*8, sB + (i*256 + wid*64)*8);
    }
  };

  const int NK = K >> 5;
  stage(0, sA0, sB0);
  for (int kk = 0; kk < NK; kk++) {
    f16* cA = (kk & 1) ? sA1 : sA0;
    f16* cB = (kk & 1) ? sB1 : sB0;
    __syncthreads();                    // own-vmcnt drain => tile kk staged
    if (kk + 1 < NK)                    // prefetch kk+1, hidden under compute
      stage((kk + 1) << 5, (kk & 1) ? sA0 : sA1, (kk & 1) ? sB0 : sB1);
    f16x8 af[4], bf[4];
    #pragma unroll
    for (int t = 0; t < 4; t++) {
      int ra = wm*64 + t*16 + lane15;
      af[t] = *(const f16x8*)(cA + ra*32 + ((quad ^ ((ra >> 1) & 3)) << 3));
      int rb = wn*64 + t*16 + lane15;
      bf[t] = *(const f16x8*)(cB + rb*32 + ((quad ^ ((rb >> 1) & 3)) << 3));
    }
    #pragma unroll
    for (int mt = 0; mt < 4; mt++)
      #pragma unroll
      for (int nt = 0; nt < 4; nt++)
        acc[mt][nt] = mfma32(af[mt], bf[nt], acc[mt][nt]);
  }
}

// ---------------- QKV GEMM + bias + scale; orientation-per-region ----
__global__ __launch_bounds__(256, 4) void k_qkv(
    const f16* __restrict__ xh, const f16* __restrict__ wqh,
    const float* __restrict__ q_bias, const float* __restrict__ v_bias,
    f16* __restrict__ Qh, f16* __restrict__ Kh, f16* __restrict__ Vt)
{
  __shared__ f16 smem[16384];           // 32 KB gemm dbuf
  f32x4 acc[4][4];
  const f32x4 z4 = {0.f, 0.f, 0.f, 0.f};
  #pragma unroll
  for (int a = 0; a < 4; a++)
    #pragma unroll
    for (int b = 0; b < 4; b++) acc[a][b] = z4;

  const int tid = threadIdx.x, wid = tid >> 6, lane = tid & 63;
  const int lane15 = lane & 15, quad = lane >> 4;
  const int wm = wid >> 1, wn = wid & 1;
  const int cblk = blockIdx.x * 128;    // qkv-channel block [0, 2304)
  const int mblk = blockIdx.y * 128;    // seq-row block    [0, 8192)
  const int bb = mblk >> 11, nbase = mblk & (SEQ - 1);
  const float QS = 0.125f * 1.4426950408889634f;   // scale * log2(e)

  if (cblk < 2*DIM) {
    // ---- Q/K: swapped GEMM: C[c][m] = W[c]·x[m]
    gemm_tile(wqh, xh, DIM, DIM, DIM, cblk, mblk, smem, acc);
    const bool isQ = (cblk < DIM);
    #pragma unroll
    for (int mt = 0; mt < 4; mt++) {
      int c0 = cblk + wm*64 + mt*16 + quad*4;          // 4 contig channels
      int cr = isQ ? c0 : (c0 - DIM);
      int h = cr >> 6, d0 = cr & 63;
      float4 qb4 = isQ ? *(const float4*)(q_bias + c0) : make_float4(0,0,0,0);
      f16* dst = isQ ? Qh : Kh;
      f16* base = dst + (((size_t)(bb*NHEAD + h)*SEQ + nbase) << 6) + d0;
      #pragma unroll
      for (int nt = 0; nt < 4; nt++) {
        int n = wn*64 + nt*16 + lane15;                // seq rel
        f32x4 v = acc[mt][nt];
        f16x4 hv;
        if (isQ) {
          hv[0] = (f16)((v[0] + qb4.x) * QS); hv[1] = (f16)((v[1] + qb4.y) * QS);
          hv[2] = (f16)((v[2] + qb4.z) * QS); hv[3] = (f16)((v[3] + qb4.w) * QS);
        } else {
          hv[0] = (f16)v[0]; hv[1] = (f16)v[1]; hv[2] = (f16)v[2]; hv[3] = (f16)v[3];
        }
        *(f16x4*)(base + ((size_t)n << 6)) = hv;
      }
    }
  } else {
    // ---- V: unswapped GEMM: C[m][c] = x[m]·W[c]
    gemm_tile(xh, wqh, DIM, DIM, DIM, mblk, cblk, smem, acc);
    #pragma unroll
    for (int nt = 0; nt < 4; nt++) {
      int c = cblk + wn*64 + nt*16 + lane15;           // one channel per lane
      int c2 = c - 2*DIM;
      int h = c2 >> 6, d = c2 & 63;
      float b = v_bias[c2];
      f16* base = Vt + ((size_t)(bb*NHEAD + h)*HD + d)*SEQ + nbase;
      #pragma unroll
      for (int mt = 0; mt < 4; mt++) {
        int n0 = wm*64 + mt*16 + quad*4;               // 4 contig seq
        f32x4 v = acc[mt][nt];
        f16x4 hv = {(f16)(v[0]+b), (f16)(v[1]+b), (f16)(v[2]+b), (f16)(v[3]+b)};
        *(f16x4*)(base + n0) = hv;
      }
    }
  }
}

// ---------------- attention: 32x32x16 MFMA, V direct from L2, 1 barrier/tile -
// Per wave: 32 q rows. S^T(32kv x 32q) = K·Q^T via 4 mfma_32x32x16 (K in LDS,
// XOR-swizzled, DMA-staged dbuf). P^T = exp2(S^T); C-layout -> B-layout done
// in-register with cvt_pkrtz + ds_bpermute(lane^32) + cndmask (bulletproof
// semantics; permlane32_swap asm produced a kv-permutation => absmax 0.094).
// PV: V^T A-frags are contiguous 16B reads straight from Vt (L1/L2-resident)
// -> no sV staging, no 2nd barrier. Row sums via ones-A mfma (permutation-
// insensitive).
#define KVT 128
#define NIT (SEQ/KVT)
__global__ __launch_bounds__(256, 3) void k_attn(
    const f16* __restrict__ Qh, const f16* __restrict__ Kh,
    const f16* __restrict__ Vt, f16* __restrict__ attnh)
{
  __shared__ f16 smem[16384];           // K dbuf 2x16KB; reused by epilogue
  f16* sK0 = smem;
  f16* sK1 = smem + 8192;

  const int tid = threadIdx.x, wid = tid >> 6, lane = tid & 63;
  const int l31 = lane & 31, hi = lane >> 5;

  // XCD-co-locating remap: all 16 q-blocks of a bh land on the same XCD
  // (dispatch xcd = linear_id % 8; 768 = 8*96 -> bijective)
  const int L = blockIdx.x;
  const int xcd = L & 7, kk = L >> 3;
  const int bh = xcd + 8*(kk >> 4);
  const int q0 = (kk & 15) * 128;
  const int qw = q0 + wid*32;

  const f16* Kbh = Kh + (size_t)bh*SEQ*HD;
  const f16* Vbh = Vt + (size_t)bh*HD*SEQ;

  // Q B-frags for 32x32x16: n=l31 (q), k=hi*8+j (d within 16-slice)
  f16x8 qf[4];
  #pragma unroll
  for (int ks = 0; ks < 4; ks++)
    qf[ks] = *(const f16x8*)(Qh + ((size_t)bh*SEQ + qw + l31)*HD + ks*16 + hi*8);

  const f32x16 z16 = {0.f,0.f,0.f,0.f, 0.f,0.f,0.f,0.f,
                      0.f,0.f,0.f,0.f, 0.f,0.f,0.f,0.f};
  f32x16 o0 = z16, o1 = z16, sacc = z16;
  f16x8 one8;
  #pragma unroll
  for (int j = 0; j < 8; j++) one8[j] = (f16)1.f;

  auto stageK = [&](int kv0, f16* sK) {
    #pragma unroll
    for (int i = 0; i < 4; i++) {
      int j = i*256 + tid;
      int row = j >> 3;
      int sc  = (j & 7) ^ (row & 7);
      gl2lds16(Kbh + (size_t)(kv0 + row)*HD + sc*8, sK + (i*256 + wid*64)*8);
    }
  };

  // hoisted swizzled LDS offsets (halves): row=c*32+l31, chunk=(2ks+hi)^(row&7)
  int koff[4];
  #pragma unroll
  for (int ks = 0; ks < 4; ks++)
    koff[ks] = l31*64 + (((2*ks + hi) ^ (l31 & 7)) << 3);

  const f16* vb0 = Vbh + (size_t)l31*SEQ + hi*8;        // d rows 0-31
  const f16* vb1 = Vbh + (size_t)(32 + l31)*SEQ + hi*8; // d rows 32-63

  const int pidx = (lane ^ 32) << 2;    // ds_bpermute byte index: partner lane

  stageK(0, sK0);

  for (int it = 0; it < NIT; it++) {
    f16* cK = (it & 1) ? sK1 : sK0;
    __syncthreads();                    // own-vmcnt drain => K(it) staged
    if (it + 1 < NIT)                   // prefetch K(it+1) under compute
      stageK((it + 1)*KVT, (it & 1) ? sK0 : sK1);

    #pragma unroll
    for (int c = 0; c < 4; c++) {
      const int p = it*KVT + c*32;
      // V A-frags (m=d=l31, k=hi*8+j -> kv): issued early, used after exp
      f16x8 va00 = *(const f16x8*)(vb0 + p);
      f16x8 va01 = *(const f16x8*)(vb0 + p + 16);
      f16x8 va10 = *(const f16x8*)(vb1 + p);
      f16x8 va11 = *(const f16x8*)(vb1 + p + 16);

      // S^T = K·Q^T over d=64 (A=K: m=kv=l31, k=hi*8+j)
      f32x16 s = z16;
      #pragma unroll
      for (int ks = 0; ks < 4; ks++) {
        f16x8 ka = *(const f16x8*)(cK + c*2048 + koff[ks]);
        s = mfma3232(ka, qf[ks], s);
      }

      // P^T = exp2(S^T), packed to f16 pairs.
      // Lane (l31,hi) reg r holds kv = (r&3)+8*(r>>2)+4*hi, q=l31.
      // h[i] packs regs (2i,2i+1):
      //  hi=0: h0={0,1} h1={2,3} h2={8,9}  h3={10,11} h4={16,17} h5={18,19} h6={24,25} h7={26,27}
      //  hi=1: h0={4,5} h1={6,7} h2={12,13} h3={14,15} h4={20,21} h5={22,23} h6={28,29} h7={30,31}
      unsigned h[8];
      #pragma unroll
      for (int r = 0; r < 8; r++) {
        union { h16x2 p2; unsigned u; } uu;
        uu.p2 = __builtin_amdgcn_cvt_pkrtz(exp2f(s[2*r]), exp2f(s[2*r+1]));
        h[r] = uu.u;
      }
      // C-layout -> B-layout (k=hi*8+j): exchange with partner lane (lane^32).
      // Target b0 (kv 0..15): hi=0 wants {0,1}{2,3}{4,5}{6,7} = {h0,h1,Ph0,Ph1}
      //                       hi=1 wants {8..15}              = {Ph2,Ph3,h2,h3}
      // Target b1 (kv 16..31): same with h4..h7.  Ph_r = partner's h[r].
      int X0 = __builtin_amdgcn_ds_bpermute(pidx, (int)h[0]);
      int X1 = __builtin_amdgcn_ds_bpermute(pidx, (int)h[1]);
      int X2 = __builtin_amdgcn_ds_bpermute(pidx, (int)h[2]);
      int X3 = __builtin_amdgcn_ds_bpermute(pidx, (int)h[3]);
      int X4 = __builtin_amdgcn_ds_bpermute(pidx, (int)h[4]);
      int X5 = __builtin_amdgcn_ds_bpermute(pidx, (int)h[5]);
      int X6 = __builtin_amdgcn_ds_bpermute(pidx, (int)h[6]);
      int X7 = __builtin_amdgcn_ds_bpermute(pidx, (int)h[7]);
      union { unsigned w[4]; f16x8 v; } b0u, b1u;
      b0u.w[0] = hi ? (unsigned)X2 : h[0];
      b0u.w[1] = hi ? (unsigned)X3 : h[1];
      b0u.w[2] = hi ? h[2] : (unsigned)X0;
      b0u.w[3] = hi ? h[3] : (unsigned)X1;
      b1u.w[0] = hi ? (unsigned)X6 : h[4];
      b1u.w[1] = hi ? (unsigned)X7 : h[5];
      b1u.w[2] = hi ? h[6] : (unsigned)X4;
      b1u.w[3] = hi ? h[7] : (unsigned)X5;

      // row sums (ones-A, permutation-insensitive) + O^T += V^T·P^T
      sacc = mfma3232(one8, b0u.v, sacc);
      sacc = mfma3232(one8, b1u.v, sacc);
      o0 = mfma3232(va00, b0u.v, o0);
      o0 = mfma3232(va01, b1u.v, o0);
      o1 = mfma3232(va10, b0u.v, o1);
      o1 = mfma3232(va11, b1u.v, o1);
    }
  }

  const float inv = 1.f / sacc[0];      // full denominator for q=l31

  // epilogue: transpose O^T -> [q][d] via LDS (reuse sK region), store coalesced
  // stride 72 halves = 144B (16B-aligned rows; proven pattern)
  __syncthreads();                      // all waves done reading sK
  f16* tb = smem + wid * (32 * 72);     // 32 rows x 72 halves per wave
  #pragma unroll
  for (int g = 0; g < 4; g++) {
    // o reg r=4g+e -> d = e + 8g + 4hi (+32 for o1): 4 contig halves
    f16x4 h0v = {(f16)(o0[4*g+0]*inv), (f16)(o0[4*g+1]*inv),
                 (f16)(o0[4*g+2]*inv), (f16)(o0[4*g+3]*inv)};
    *(f16x4*)(tb + l31*72 + g*8 + hi*4) = h0v;
    f16x4 h1v = {(f16)(o1[4*g+0]*inv), (f16)(o1[4*g+1]*inv),
                 (f16)(o1[4*g+2]*inv), (f16)(o1[4*g+3]*inv)};
    *(f16x4*)(tb + l31*72 + 32 + g*8 + hi*4) = h1v;
  }
  __syncthreads();
  const int b = bh / NHEAD, hh = bh % NHEAD;
  #pragma unroll
  for (int i = 0; i < 4; i++) {
    int row = i*8 + (lane >> 3);        // 8 rows per pass, 8 lanes per row
    f16x8 rv = *(const f16x8*)(tb + row*72 + (lane & 7)*8);
    *(f16x8*)(attnh + ((size_t)b*SEQ + qw + row)*DIM + hh*HD + (lane & 7)*8) = rv;
  }
}

// ---------------- proj GEMM + bias, fp32 output (swapped: float4 stores) ----
__global__ __launch_bounds__(256, 4) void k_proj(
    const f16* __restrict__ ah, const f16* __restrict__ wph,
    const float* __restrict__ pbias, float* __restrict__ out)
{
  __shared__ f16 smem[16384];           // 32 KB gemm dbuf
  f32x4 acc[4][4];
  const f32x4 z4 = {0.f, 0.f, 0.f, 0.f};
  #pragma unroll
  for (int a = 0; a < 4; a++)
    #pragma unroll
    for (int b = 0; b < 4; b++) acc[a][b] = z4;

  const int cblk = blockIdx.y * 128;    // out-channel block [0, 768)
  const int mblk = blockIdx.x * 128;    // seq-row block     [0, 8192)
  gemm_tile(wph, ah, DIM, DIM, DIM, cblk, mblk, smem, acc);

  const int tid = threadIdx.x, wid = tid >> 6, lane = tid & 63;
  const int lane15 = lane & 15, quad = lane >> 4;
  const int wm = wid >> 1, wn = wid & 1;
  #pragma unroll
  for (int mt = 0; mt < 4; mt++) {
    int c0 = cblk + wm*64 + mt*16 + quad*4;            // 4 contig channels
    float4 b4 = *(const float4*)(pbias + c0);
    #pragma unroll
    for (int nt = 0; nt < 4; nt++) {
      int m = mblk + wn*64 + nt*16 + lane15;           // seq
      f32x4 v = acc[mt][nt];
      float4 r = make_float4(v[0]+b4.x, v[1]+b4.y, v[2]+b4.z, v[3]+b4.w);
      *(float4*)(out + (size_t)m*DIM + c0) = r;
    }
  }
}

extern "C" void kernel_launch(void* const* d_in, const int* in_sizes, int n_in,
                              void* d_out, int out_size, void* d_ws, size_t ws_size,
                              hipStream_t stream) {
  const float* x    = (const float*)d_in[0];
  const float* wqkv = (const float*)d_in[1];
  const float* qb   = (const float*)d_in[2];
  const float* vb   = (const float*)d_in[3];
  const float* wp   = (const float*)d_in[4];
  const float* pb   = (const float*)d_in[5];
  float* out = (float*)d_out;

  f16* p = (f16*)d_ws;
  f16* xh  = p; p += (size_t)MROWS*DIM;
  f16* wqh = p; p += (size_t)C3*DIM;
  f16* wph = p; p += (size_t)DIM*DIM;
  f16* Qh  = p; p += (size_t)NBH*SEQ*HD;
  f16* Kh  = p; p += (size_t)NBH*SEQ*HD;
  f16* Vt  = p; p += (size_t)NBH*SEQ*HD;
  f16* attnh = xh;                      // xh dead after k_qkv -> reuse

  k_convert<<<8448, 256, 0, stream>>>(x, wqkv, wp, xh, wqh, wph);
  k_qkv<<<dim3(C3/128, MROWS/128), 256, 0, stream>>>(xh, wqh, qb, vb, Qh, Kh, Vt);
  k_attn<<<dim3((SEQ/128)*NBH), 256, 0, stream>>>(Qh, Kh, Vt, attnh);
  k_proj<<<dim3(MROWS/128, DIM/128), 256, 0, stream>>>(attnh, wph, pb, out);
}